// Round 15
// baseline (342.671 us; speedup 1.0000x reference)
//
#include <hip/hip_runtime.h>
#include <math.h>

using bf16x8 = __attribute__((ext_vector_type(8))) short;
using f32x4  = __attribute__((ext_vector_type(4))) float;

// ---- bf16 helpers ----
__device__ __forceinline__ unsigned short f2bf(float v) {          // RNE pack
  unsigned int b = __float_as_uint(v);
  unsigned int r = (b + 0x7fffu + ((b >> 16) & 1u)) >> 16;
  return (unsigned short)r;
}
__device__ __forceinline__ float bf2f(unsigned short u) {
  return __uint_as_float(((unsigned int)u) << 16);
}

// ============================ weight pack (W0 + W1 merged, proven R9) ============================

__global__ void pack_w_kernel(const float* __restrict__ W0f, unsigned short* __restrict__ Bp0,
                              const float* __restrict__ W1f, unsigned short* __restrict__ Bp1) {
  int idx = blockIdx.x * 256 + threadIdx.x;
  if (idx < 8192) {
    int lane = idx & 63, s = (idx >> 6) & 7, t = idx >> 9;
    int n = t * 16 + (lane & 15), quad = lane >> 4;
    unsigned short* o = Bp0 + (size_t)idx * 8;
    #pragma unroll
    for (int j = 0; j < 8; ++j) {
      int k = s * 32 + quad * 8 + j;
      o[j] = f2bf(W0f[(size_t)k * 256 + n]);
    }
  } else if (idx < 8192 + 1536) {
    int i1 = idx - 8192;
    int lane = i1 & 63, s = (i1 >> 6) & 7, t = i1 >> 9;
    int n = t * 16 + (lane & 15), quad = lane >> 4;
    unsigned short* o = Bp1 + (size_t)i1 * 8;
    #pragma unroll
    for (int j = 0; j < 8; ++j) {
      int k = s * 32 + quad * 8 + j;
      o[j] = (n < 40) ? f2bf(W1f[(size_t)k * 40 + n]) : 0;
    }
  }
}

// ============================ mega1 v2: gemm0 (32 KB LDS, 256 rows x 64-col quarter) || hist ============================
// Block < nG: gx = bx>>2 (256-row group), y = bx&3 (64-col quarter == head y).
// All 4 waves share the quarter's 32 KB of packed W0 -> 4 blocks/CU (vs 2 at 64 KB).
// Wave work identical to R12-proven body (4x4 acc tiles of 64x64).

__global__ __launch_bounds__(256) void mega1_kernel(
    const float* __restrict__ A, const unsigned short* __restrict__ Bp,
    unsigned short* __restrict__ Zb,
    const float* __restrict__ al, const float* __restrict__ arr,
    float* __restrict__ el, float* __restrict__ er, int M,
    const int* __restrict__ dst, int* __restrict__ deg, int E, int nG) {
  __shared__ unsigned short Bs[16384];           // 32 KB: one 64-col quarter
  int bx = blockIdx.x;

  if (bx >= nG) {                                // ---- hist part ----
    int t = (bx - nG) * 256 + threadIdx.x;
    if (t < E) atomicAdd(&deg[dst[t]], 1);
    return;
  }

  // ---- gemm0 part ----
  int gx = bx >> 2, y = bx & 3;                  // y = col quarter = head
  int tid = threadIdx.x;
  {                                              // stage 32 KB = 2048 int4
    const int4* s4 = (const int4*)(Bp + (size_t)y * 16384);
    int4* d4 = (int4*)Bs;
    #pragma unroll
    for (int i = 0; i < 8; ++i) d4[tid + i * 256] = s4[tid + i * 256];
  }
  __syncthreads();

  int wid = tid >> 6, lane = tid & 63;
  int quad = lane >> 4, col16 = lane & 15;
  int rowbase = gx * 256 + wid * 64;

  f32x4 acc[4][4];
  #pragma unroll
  for (int rt = 0; rt < 4; ++rt)
    #pragma unroll
    for (int ct = 0; ct < 4; ++ct) acc[rt][ct] = {0.f, 0.f, 0.f, 0.f};

  const bf16x8* BsV = (const bf16x8*)Bs;

  for (int s = 0; s < 8; ++s) {
    bf16x8 af[4];
    #pragma unroll
    for (int rt = 0; rt < 4; ++rt) {
      int m = rowbase + rt * 16 + col16;
      if (m < M) {
        const float* ap = A + (size_t)m * 256 + s * 32 + quad * 8;
        float4 a0 = *(const float4*)ap;
        float4 a1 = *(const float4*)(ap + 4);
        af[rt][0] = (short)f2bf(a0.x); af[rt][1] = (short)f2bf(a0.y);
        af[rt][2] = (short)f2bf(a0.z); af[rt][3] = (short)f2bf(a0.w);
        af[rt][4] = (short)f2bf(a1.x); af[rt][5] = (short)f2bf(a1.y);
        af[rt][6] = (short)f2bf(a1.z); af[rt][7] = (short)f2bf(a1.w);
      } else {
        #pragma unroll
        for (int j = 0; j < 8; ++j) af[rt][j] = 0;
      }
    }
    #pragma unroll
    for (int ct = 0; ct < 4; ++ct) {
      bf16x8 bf = BsV[(ct * 8 + s) * 64 + lane];
      #pragma unroll
      for (int rt = 0; rt < 4; ++rt)
        acc[rt][ct] = __builtin_amdgcn_mfma_f32_16x16x32_bf16(af[rt], bf, acc[rt][ct], 0, 0, 0);
    }
  }

  // ---- epilogue: Zb writes + fused el/er (head y) ----
  float al_c[4], ar_c[4];
  #pragma unroll
  for (int ct = 0; ct < 4; ++ct) {
    int col = y * 64 + ct * 16 + col16;
    al_c[ct] = al[col];
    ar_c[ct] = arr[col];
  }

  #pragma unroll
  for (int rt = 0; rt < 4; ++rt) {
    int row0 = rowbase + rt * 16 + quad * 4;
    #pragma unroll
    for (int r = 0; r < 4; ++r) {
      int row = row0 + r;
      if (row < M) {
        #pragma unroll
        for (int ct = 0; ct < 4; ++ct) {
          int col = y * 64 + ct * 16 + col16;
          Zb[(size_t)row * 256 + col] = f2bf(acc[rt][ct][r]);
        }
      }
      float pe = 0.f, pr = 0.f;
      #pragma unroll
      for (int ct = 0; ct < 4; ++ct) {
        float zv = acc[rt][ct][r];
        pe += zv * al_c[ct];
        pr += zv * ar_c[ct];
      }
      pe += __shfl_xor(pe, 1); pr += __shfl_xor(pr, 1);
      pe += __shfl_xor(pe, 2); pr += __shfl_xor(pr, 2);
      pe += __shfl_xor(pe, 4); pr += __shfl_xor(pr, 4);
      pe += __shfl_xor(pe, 8); pr += __shfl_xor(pr, 8);
      if (col16 == 0 && row < M) {
        el[(size_t)row * 4 + y] = pe;
        er[(size_t)row * 4 + y] = pr;
      }
    }
  }
}

// ============================ 3-phase parallel scan (proven R5-R12) ============================

__global__ void block_sum_kernel(const int* __restrict__ deg, int* __restrict__ bsum, int n) {
  __shared__ int red[4];
  int t = threadIdx.x, i = blockIdx.x * 256 + t;
  int v = (i < n) ? deg[i] : 0;
  #pragma unroll
  for (int off = 32; off; off >>= 1) v += __shfl_xor(v, off);
  if ((t & 63) == 0) red[t >> 6] = v;
  __syncthreads();
  if (t == 0) bsum[blockIdx.x] = red[0] + red[1] + red[2] + red[3];
}

__global__ void scan_bsum_kernel(const int* __restrict__ bsum, int* __restrict__ boffs,
                                 int* __restrict__ offsets, int nb, int n) {
  __shared__ int tmp[1024];
  int t = threadIdx.x;
  int v = (t < nb) ? bsum[t] : 0;
  tmp[t] = v;
  __syncthreads();
  #pragma unroll
  for (int off = 1; off < 1024; off <<= 1) {
    int add = (t >= off) ? tmp[t - off] : 0;
    __syncthreads();
    tmp[t] += add;
    __syncthreads();
  }
  if (t < nb) boffs[t] = tmp[t] - v;
  if (t == 1023) offsets[n] = tmp[1023];
}

__global__ void write_offsets_kernel(const int* __restrict__ deg, const int* __restrict__ boffs,
                                     int* __restrict__ offsets, int* __restrict__ cursor, int n) {
  __shared__ int tmp[256];
  int t = threadIdx.x, i = blockIdx.x * 256 + t;
  int v = (i < n) ? deg[i] : 0;
  tmp[t] = v;
  __syncthreads();
  #pragma unroll
  for (int off = 1; off < 256; off <<= 1) {
    int add = (t >= off) ? tmp[t - off] : 0;
    __syncthreads();
    tmp[t] += add;
    __syncthreads();
  }
  if (i < n) {
    int o = boffs[blockIdx.x] + tmp[t] - v;
    offsets[i] = o;
    cursor[i] = o;
  }
}

__global__ void build_csr_kernel(const int* __restrict__ src, const int* __restrict__ dst,
                                 int* __restrict__ cursor, int* __restrict__ src_sorted, int E) {
  int e = blockIdx.x * blockDim.x + threadIdx.x;
  if (e < E) {
    int p = atomicAdd(&cursor[dst[e]], 1);
    src_sorted[p] = src[e];
  }
}

// ============================ layer-1 GEMM (proven R9) ============================

__global__ __launch_bounds__(256) void gemm1_mfma_kernel(
    const unsigned short* __restrict__ Ab, const unsigned short* __restrict__ Bp,
    unsigned short* __restrict__ Zb,
    const float* __restrict__ al, const float* __restrict__ arr,
    float* __restrict__ el, float* __restrict__ er, int M) {
  int wid = threadIdx.x >> 6, lane = threadIdx.x & 63;
  int quad = lane >> 4, col16 = lane & 15;
  int m = blockIdx.x * 64 + wid * 16 + col16;

  f32x4 acc[3];
  #pragma unroll
  for (int t = 0; t < 3; ++t) acc[t] = {0.f, 0.f, 0.f, 0.f};

  const bf16x8* BpV = (const bf16x8*)Bp;

  for (int s = 0; s < 8; ++s) {
    bf16x8 af;
    if (m < M) {
      af = *(const bf16x8*)(Ab + (size_t)m * 256 + s * 32 + quad * 8);
    } else {
      #pragma unroll
      for (int j = 0; j < 8; ++j) af[j] = 0;
    }
    #pragma unroll
    for (int t = 0; t < 3; ++t) {
      bf16x8 bf = BpV[(t * 8 + s) * 64 + lane];
      acc[t] = __builtin_amdgcn_mfma_f32_16x16x32_bf16(af, bf, acc[t], 0, 0, 0);
    }
  }

  float al_c[3], ar_c[3];
  #pragma unroll
  for (int t = 0; t < 3; ++t) {
    int col = t * 16 + col16;
    al_c[t] = (col < 40) ? al[col] : 0.f;
    ar_c[t] = (col < 40) ? arr[col] : 0.f;
  }

  int row0 = blockIdx.x * 64 + wid * 16 + quad * 4;
  #pragma unroll
  for (int r = 0; r < 4; ++r) {
    int row = row0 + r;
    if (row < M) {
      #pragma unroll
      for (int t = 0; t < 3; ++t) {
        int col = t * 16 + col16;
        if (col < 40) Zb[(size_t)row * 40 + col] = f2bf(acc[t][r]);
      }
    }
    float pe = 0.f, pr = 0.f;
    #pragma unroll
    for (int t = 0; t < 3; ++t) {
      pe += acc[t][r] * al_c[t];
      pr += acc[t][r] * ar_c[t];
    }
    pe += __shfl_xor(pe, 1); pr += __shfl_xor(pr, 1);
    pe += __shfl_xor(pe, 2); pr += __shfl_xor(pr, 2);
    pe += __shfl_xor(pe, 4); pr += __shfl_xor(pr, 4);
    pe += __shfl_xor(pe, 8); pr += __shfl_xor(pr, 8);
    if (col16 == 0 && row < M) {
      el[row] = pe;
      er[row] = pr;
    }
  }
}

// ============================ layer-0 aggregation (proven R12) ============================

__global__ __launch_bounds__(256) void agg0_kernel(
    const int* __restrict__ offs, const int* __restrict__ ssrc,
    const float* __restrict__ el, const float* __restrict__ er,
    const unsigned short* __restrict__ zb, const float* __restrict__ bias,
    unsigned short* __restrict__ outb, int n) {
  __shared__ float sW[4][16][4];
  __shared__ int   sS[4][16];
  int wid  = threadIdx.x >> 6;
  int lane = threadIdx.x & 63;
  int node = blockIdx.x * 4 + wid;
  if (node >= n) return;
  int c = lane & 3, eoff = lane >> 2;
  int half = lane >> 5, colg = lane & 31, h2 = colg >> 3;
  int s0 = offs[node], s1 = offs[node + 1];
  float er_c = er[node * 4 + c];

  float ssum = 0.f;
  float acc[8] = {0.f, 0.f, 0.f, 0.f, 0.f, 0.f, 0.f, 0.f};
  for (int base = s0; base < s1; base += 16) {
    int cnt = min(16, s1 - base);
    if (eoff < cnt) {
      int esrc = ssrc[base + eoff];
      float v = el[esrc * 4 + c] + er_c;
      v = v > 0.f ? v : 0.2f * v;              // leaky_relu(0.2)
      sW[wid][eoff][c] = expf(v);              // no max-shift (scores O(+-10))
      if (c == 0) sS[wid][eoff] = esrc;
    }
    for (int j = 0; j < cnt; j += 2) {
      int jj = j + half;
      float w = (jj < cnt) ? sW[wid][jj][h2] : 0.f;
      int sn = sS[wid][(jj < cnt) ? jj : (cnt - 1)];
      ssum += w;
      bf16x8 zu = *(const bf16x8*)(zb + (size_t)sn * 256 + (colg << 3));
      #pragma unroll
      for (int i = 0; i < 8; ++i)
        acc[i] += w * bf2f((unsigned short)zu[i]);
    }
  }

  ssum += __shfl_xor(ssum, 32);
  #pragma unroll
  for (int i = 0; i < 8; ++i) acc[i] += __shfl_xor(acc[i], 32);

  float inv = (s1 > s0) ? 1.f / ssum : 0.f;    // deg==0 -> out = bias
  if (half == 0) {
    const float4 b0v = *(const float4*)(bias + (colg << 3));
    const float4 b1v = *(const float4*)(bias + (colg << 3) + 4);
    float bb[8] = {b0v.x, b0v.y, b0v.z, b0v.w, b1v.x, b1v.y, b1v.z, b1v.w};
    bf16x8 u;
    #pragma unroll
    for (int i = 0; i < 8; ++i) {
      float o = acc[i] * inv + bb[i];
      o = o > 0.f ? o : expm1f(o);             // ELU
      u[i] = (short)f2bf(o);
    }
    *(bf16x8*)(outb + (size_t)node * 256 + (colg << 3)) = u;
  }
}

// ============================ layer-1 aggregation (proven R12) ============================

__global__ __launch_bounds__(256) void agg1_kernel(
    const int* __restrict__ offs, const int* __restrict__ ssrc,
    const float* __restrict__ el, const float* __restrict__ er,
    const unsigned short* __restrict__ zb, const float* __restrict__ bias,
    float* __restrict__ out, int n) {
  __shared__ float sW[4][64];
  __shared__ int   sS[4][64];
  int wid  = threadIdx.x >> 6;
  int lane = threadIdx.x & 63;
  int node = blockIdx.x * 4 + wid;
  if (node >= n) return;
  int half = lane >> 5, d = lane & 31;
  int s0 = offs[node], s1 = offs[node + 1];
  float ern = er[node];

  float ssum = 0.f;
  float2 acc = make_float2(0.f, 0.f);
  for (int base = s0; base < s1; base += 64) {
    int cnt = min(64, s1 - base);
    if (lane < cnt) {
      int esrc = ssrc[base + lane];
      float v = el[esrc] + ern;
      v = v > 0.f ? v : 0.2f * v;
      sW[wid][lane] = expf(v);                 // no max-shift
      sS[wid][lane] = esrc;
    }
    for (int j = 0; j < cnt; j += 2) {
      int jj = j + half;
      float w = (jj < cnt) ? sW[wid][jj] : 0.f;
      int sn = sS[wid][(jj < cnt) ? jj : (cnt - 1)];
      ssum += w;
      if (d < 20) {
        unsigned zp = *(const unsigned*)(zb + (size_t)sn * 40 + (d << 1));
        acc.x += w * bf2f((unsigned short)(zp & 0xffffu));
        acc.y += w * bf2f((unsigned short)(zp >> 16));
      }
    }
  }

  ssum  += __shfl_xor(ssum, 32);
  acc.x += __shfl_xor(acc.x, 32);
  acc.y += __shfl_xor(acc.y, 32);

  float inv = (s1 > s0) ? 1.f / ssum : 0.f;
  if (half == 0 && d < 20) {
    float2 o;
    o.x = acc.x * inv + bias[(d << 1) + 0];
    o.y = acc.y * inv + bias[(d << 1) + 1];
    *(float2*)(out + (size_t)node * 40 + (d << 1)) = o;
  }
}

// ============================ launch ============================

extern "C" void kernel_launch(void* const* d_in, const int* in_sizes, int n_in,
                              void* d_out, int out_size, void* d_ws, size_t ws_size,
                              hipStream_t stream) {
  const float* x   = (const float*)d_in[0];
  const int*   src = (const int*)d_in[1];
  const int*   dst = (const int*)d_in[2];
  const float* W0  = (const float*)d_in[3];
  const float* al0 = (const float*)d_in[4];
  const float* ar0 = (const float*)d_in[5];
  const float* b0  = (const float*)d_in[6];
  const float* W1  = (const float*)d_in[7];
  const float* al1 = (const float*)d_in[8];
  const float* ar1 = (const float*)d_in[9];
  const float* b1  = (const float*)d_in[10];
  float* out = (float*)d_out;

  const int N = in_sizes[0] / 256;   // 50000
  const int E = in_sizes[1];         // 800000
  const int NB = (N + 255) / 256;    // 196 scan blocks

  char* ws = (char*)d_ws;
  size_t off = 0;
  auto alloc = [&](size_t bytes) {
    void* p = ws + off;
    off = (off + bytes + 255) & ~(size_t)255;
    return p;
  };
  unsigned short* z0b = (unsigned short*)alloc((size_t)N * 256 * 2);
  unsigned short* h0b = (unsigned short*)alloc((size_t)N * 256 * 2);
  unsigned short* z1b = (unsigned short*)alloc((size_t)N * 40 * 2);
  unsigned short* w0p = (unsigned short*)alloc((size_t)16 * 8 * 64 * 8 * 2);
  unsigned short* w1p = (unsigned short*)alloc((size_t)3 * 8 * 64 * 8 * 2);
  float* el0  = (float*)alloc((size_t)N * 4 * 4);
  float* er0  = (float*)alloc((size_t)N * 4 * 4);
  float* el1  = (float*)alloc((size_t)N * 4);
  float* er1  = (float*)alloc((size_t)N * 4);
  int* deg    = (int*)alloc((size_t)N * 4);
  int* offs   = (int*)alloc((size_t)(N + 1) * 4);
  int* cursor = (int*)alloc((size_t)N * 4);
  int* bsum   = (int*)alloc((size_t)NB * 4);
  int* boffs  = (int*)alloc((size_t)NB * 4);
  int* ssrc   = (int*)alloc((size_t)E * 4);
  (void)off; (void)ws_size; (void)n_in; (void)out_size;

  const int nG = ((N + 255) / 256) * 4;          // 784 gemm0 blocks (256-row x 64-col quarter)
  const int nH = (E + 255) / 256;                // 3125 hist blocks

  // 1. weight packs (gemm0 inside mega1 needs w0p)
  pack_w_kernel<<<38, 256, 0, stream>>>(W0, w0p, W1, w1p);
  // 2. deg = 0 (driver memset; hist inside mega1 needs it)
  hipMemsetAsync(deg, 0, (size_t)N * 4, stream);
  // 3. gemm0 || hist in one dispatch (32 KB LDS -> 4 blocks/CU)
  mega1_kernel<<<nG + nH, 256, 0, stream>>>(x, w0p, z0b, al0, ar0, el0, er0, N,
                                            dst, deg, E, nG);
  // 4-6. exclusive scan, 3-phase (proven R5-R12)
  block_sum_kernel<<<NB, 256, 0, stream>>>(deg, bsum, N);
  scan_bsum_kernel<<<1, 1024, 0, stream>>>(bsum, boffs, offs, NB, N);
  write_offsets_kernel<<<NB, 256, 0, stream>>>(deg, boffs, offs, cursor, N);
  // 7. CSR scatter
  build_csr_kernel<<<nH, 256, 0, stream>>>(src, dst, cursor, ssrc, E);
  // 8. layer-0 aggregation + ELU -> h0b
  agg0_kernel<<<(N + 3) / 4, 256, 0, stream>>>(offs, ssrc, el0, er0, z0b, b0, h0b, N);
  // 9. layer-1 GEMM + fused el/er
  gemm1_mfma_kernel<<<(N + 63) / 64, 256, 0, stream>>>(h0b, w1p, z1b, al1, ar1, el1, er1, N);
  // 10. layer-1 aggregation -> out
  agg1_kernel<<<(N + 3) / 4, 256, 0, stream>>>(offs, ssrc, el1, er1, z1b, b1, out, N);
}

// Round 16
// 322.388 us; speedup vs baseline: 1.0629x; 1.0629x over previous
//
#include <hip/hip_runtime.h>
#include <math.h>

using bf16x8 = __attribute__((ext_vector_type(8))) short;
using f32x4  = __attribute__((ext_vector_type(4))) float;

// ---- bf16 helpers ----
__device__ __forceinline__ unsigned short f2bf(float v) {          // RNE pack
  unsigned int b = __float_as_uint(v);
  unsigned int r = (b + 0x7fffu + ((b >> 16) & 1u)) >> 16;
  return (unsigned short)r;
}
__device__ __forceinline__ float bf2f(unsigned short u) {
  return __uint_as_float(((unsigned int)u) << 16);
}

// ============================ mega0: pack (blocks 0..37) || hist (blocks 38..) ============================
// No LDS -> hist atomics run at full occupancy.

__global__ void mega0_kernel(const float* __restrict__ W0f, unsigned short* __restrict__ Bp0,
                             const float* __restrict__ W1f, unsigned short* __restrict__ Bp1,
                             const int* __restrict__ dst, int* __restrict__ deg, int E) {
  int bx = blockIdx.x;
  if (bx >= 38) {                                // ---- hist ----
    int t = (bx - 38) * 256 + threadIdx.x;
    if (t < E) atomicAdd(&deg[dst[t]], 1);
    return;
  }
  // ---- weight pack (proven R9) ----
  int idx = bx * 256 + threadIdx.x;
  if (idx < 8192) {
    int lane = idx & 63, s = (idx >> 6) & 7, t = idx >> 9;
    int n = t * 16 + (lane & 15), quad = lane >> 4;
    unsigned short* o = Bp0 + (size_t)idx * 8;
    #pragma unroll
    for (int j = 0; j < 8; ++j) {
      int k = s * 32 + quad * 8 + j;
      o[j] = f2bf(W0f[(size_t)k * 256 + n]);
    }
  } else if (idx < 8192 + 1536) {
    int i1 = idx - 8192;
    int lane = i1 & 63, s = (i1 >> 6) & 7, t = i1 >> 9;
    int n = t * 16 + (lane & 15), quad = lane >> 4;
    unsigned short* o = Bp1 + (size_t)i1 * 8;
    #pragma unroll
    for (int j = 0; j < 8; ++j) {
      int k = s * 32 + quad * 8 + j;
      o[j] = (n < 40) ? f2bf(W1f[(size_t)k * 40 + n]) : 0;
    }
  }
}

// ============================ 3-phase parallel scan (proven R5-R14) ============================

__global__ void block_sum_kernel(const int* __restrict__ deg, int* __restrict__ bsum, int n) {
  __shared__ int red[4];
  int t = threadIdx.x, i = blockIdx.x * 256 + t;
  int v = (i < n) ? deg[i] : 0;
  #pragma unroll
  for (int off = 32; off; off >>= 1) v += __shfl_xor(v, off);
  if ((t & 63) == 0) red[t >> 6] = v;
  __syncthreads();
  if (t == 0) bsum[blockIdx.x] = red[0] + red[1] + red[2] + red[3];
}

__global__ void scan_bsum_kernel(const int* __restrict__ bsum, int* __restrict__ boffs,
                                 int* __restrict__ offsets, int nb, int n) {
  __shared__ int tmp[1024];
  int t = threadIdx.x;
  int v = (t < nb) ? bsum[t] : 0;
  tmp[t] = v;
  __syncthreads();
  #pragma unroll
  for (int off = 1; off < 1024; off <<= 1) {
    int add = (t >= off) ? tmp[t - off] : 0;
    __syncthreads();
    tmp[t] += add;
    __syncthreads();
  }
  if (t < nb) boffs[t] = tmp[t] - v;
  if (t == 1023) offsets[n] = tmp[1023];
}

__global__ void write_offsets_kernel(const int* __restrict__ deg, const int* __restrict__ boffs,
                                     int* __restrict__ offsets, int* __restrict__ cursor, int n) {
  __shared__ int tmp[256];
  int t = threadIdx.x, i = blockIdx.x * 256 + t;
  int v = (i < n) ? deg[i] : 0;
  tmp[t] = v;
  __syncthreads();
  #pragma unroll
  for (int off = 1; off < 256; off <<= 1) {
    int add = (t >= off) ? tmp[t - off] : 0;
    __syncthreads();
    tmp[t] += add;
    __syncthreads();
  }
  if (i < n) {
    int o = boffs[blockIdx.x] + tmp[t] - v;
    offsets[i] = o;
    cursor[i] = o;
  }
}

// ============================ mega2: gemm0 (blocks < nG, 64 KB LDS) || build_csr (blocks >= nG) ============================
// gemm0: R14-proven 128x128 body + clamped A-rows (branch-free loads; garbage
// A-rows only affect unwritten C-rows) + explicit next-s A prefetch.
// csr: grid-stride scatter; independent of gemm0 (needs only scan output).

__global__ __launch_bounds__(256) void mega2_kernel(
    const float* __restrict__ A, const unsigned short* __restrict__ Bp,
    unsigned short* __restrict__ Zb,
    const float* __restrict__ al, const float* __restrict__ arr,
    float* __restrict__ el, float* __restrict__ er, int M,
    const int* __restrict__ src, const int* __restrict__ dst,
    int* __restrict__ cursor, int* __restrict__ ssrc, int E, int nG, int nC) {
  __shared__ unsigned short Bs[32768];           // 64 KB
  int bx = blockIdx.x;

  if (bx >= nG) {                                // ---- build_csr part ----
    int stride = nC * 256;
    for (int e = (bx - nG) * 256 + threadIdx.x; e < E; e += stride) {
      int p = atomicAdd(&cursor[dst[e]], 1);
      ssrc[p] = src[e];
    }
    return;
  }

  // ---- gemm0 part ----
  int gx = bx >> 1, y = bx & 1;
  int tid = threadIdx.x;
  {
    const int4* s4 = (const int4*)(Bp + (size_t)y * 32768);
    int4* d4 = (int4*)Bs;
    #pragma unroll
    for (int i = 0; i < 16; ++i) d4[tid + i * 256] = s4[tid + i * 256];
  }
  __syncthreads();

  int wid = tid >> 6, lane = tid & 63;
  int quad = lane >> 4, col16 = lane & 15;
  int wr = wid >> 1, wc = wid & 1;
  int rowbase = gx * 128 + wr * 64;

  // clamped row pointers (branch-free A loads)
  const float* aptr[4];
  #pragma unroll
  for (int rt = 0; rt < 4; ++rt) {
    int m = rowbase + rt * 16 + col16;
    if (m > M - 1) m = M - 1;
    aptr[rt] = A + (size_t)m * 256 + quad * 8;
  }

  f32x4 acc[4][4];
  #pragma unroll
  for (int rt = 0; rt < 4; ++rt)
    #pragma unroll
    for (int ct = 0; ct < 4; ++ct) acc[rt][ct] = {0.f, 0.f, 0.f, 0.f};

  const bf16x8* BsV = (const bf16x8*)Bs;

  auto loadA = [&](bf16x8* fr, int s) {
    #pragma unroll
    for (int rt = 0; rt < 4; ++rt) {
      const float* ap = aptr[rt] + s * 32;
      float4 a0 = *(const float4*)ap;
      float4 a1 = *(const float4*)(ap + 4);
      fr[rt][0] = (short)f2bf(a0.x); fr[rt][1] = (short)f2bf(a0.y);
      fr[rt][2] = (short)f2bf(a0.z); fr[rt][3] = (short)f2bf(a0.w);
      fr[rt][4] = (short)f2bf(a1.x); fr[rt][5] = (short)f2bf(a1.y);
      fr[rt][6] = (short)f2bf(a1.z); fr[rt][7] = (short)f2bf(a1.w);
    }
  };

  bf16x8 afc[4];
  loadA(afc, 0);
  for (int s = 0; s < 8; ++s) {
    bf16x8 afn[4];
    if (s < 7) loadA(afn, s + 1);                // prefetch next k-step
    #pragma unroll
    for (int ct = 0; ct < 4; ++ct) {
      bf16x8 bf = BsV[((wc * 4 + ct) * 8 + s) * 64 + lane];
      #pragma unroll
      for (int rt = 0; rt < 4; ++rt)
        acc[rt][ct] = __builtin_amdgcn_mfma_f32_16x16x32_bf16(afc[rt], bf, acc[rt][ct], 0, 0, 0);
    }
    if (s < 7) {
      #pragma unroll
      for (int rt = 0; rt < 4; ++rt) afc[rt] = afn[rt];
    }
  }

  int hw = y * 2 + wc;
  float al_c[4], ar_c[4];
  #pragma unroll
  for (int ct = 0; ct < 4; ++ct) {
    int col = y * 128 + (wc * 4 + ct) * 16 + col16;
    al_c[ct] = al[col];
    ar_c[ct] = arr[col];
  }

  #pragma unroll
  for (int rt = 0; rt < 4; ++rt) {
    int row0 = rowbase + rt * 16 + quad * 4;
    #pragma unroll
    for (int r = 0; r < 4; ++r) {
      int row = row0 + r;
      if (row < M) {
        #pragma unroll
        for (int ct = 0; ct < 4; ++ct) {
          int col = y * 128 + (wc * 4 + ct) * 16 + col16;
          Zb[(size_t)row * 256 + col] = f2bf(acc[rt][ct][r]);
        }
      }
      float pe = 0.f, pr = 0.f;
      #pragma unroll
      for (int ct = 0; ct < 4; ++ct) {
        float zv = acc[rt][ct][r];
        pe += zv * al_c[ct];
        pr += zv * ar_c[ct];
      }
      pe += __shfl_xor(pe, 1); pr += __shfl_xor(pr, 1);
      pe += __shfl_xor(pe, 2); pr += __shfl_xor(pr, 2);
      pe += __shfl_xor(pe, 4); pr += __shfl_xor(pr, 4);
      pe += __shfl_xor(pe, 8); pr += __shfl_xor(pr, 8);
      if (col16 == 0 && row < M) {
        el[(size_t)row * 4 + hw] = pe;
        er[(size_t)row * 4 + hw] = pr;
      }
    }
  }
}

// ============================ layer-1 GEMM (proven R9) ============================

__global__ __launch_bounds__(256) void gemm1_mfma_kernel(
    const unsigned short* __restrict__ Ab, const unsigned short* __restrict__ Bp,
    unsigned short* __restrict__ Zb,
    const float* __restrict__ al, const float* __restrict__ arr,
    float* __restrict__ el, float* __restrict__ er, int M) {
  int wid = threadIdx.x >> 6, lane = threadIdx.x & 63;
  int quad = lane >> 4, col16 = lane & 15;
  int m = blockIdx.x * 64 + wid * 16 + col16;

  f32x4 acc[3];
  #pragma unroll
  for (int t = 0; t < 3; ++t) acc[t] = {0.f, 0.f, 0.f, 0.f};

  const bf16x8* BpV = (const bf16x8*)Bp;

  for (int s = 0; s < 8; ++s) {
    bf16x8 af;
    if (m < M) {
      af = *(const bf16x8*)(Ab + (size_t)m * 256 + s * 32 + quad * 8);
    } else {
      #pragma unroll
      for (int j = 0; j < 8; ++j) af[j] = 0;
    }
    #pragma unroll
    for (int t = 0; t < 3; ++t) {
      bf16x8 bf = BpV[(t * 8 + s) * 64 + lane];
      acc[t] = __builtin_amdgcn_mfma_f32_16x16x32_bf16(af, bf, acc[t], 0, 0, 0);
    }
  }

  float al_c[3], ar_c[3];
  #pragma unroll
  for (int t = 0; t < 3; ++t) {
    int col = t * 16 + col16;
    al_c[t] = (col < 40) ? al[col] : 0.f;
    ar_c[t] = (col < 40) ? arr[col] : 0.f;
  }

  int row0 = blockIdx.x * 64 + wid * 16 + quad * 4;
  #pragma unroll
  for (int r = 0; r < 4; ++r) {
    int row = row0 + r;
    if (row < M) {
      #pragma unroll
      for (int t = 0; t < 3; ++t) {
        int col = t * 16 + col16;
        if (col < 40) Zb[(size_t)row * 40 + col] = f2bf(acc[t][r]);
      }
    }
    float pe = 0.f, pr = 0.f;
    #pragma unroll
    for (int t = 0; t < 3; ++t) {
      pe += acc[t][r] * al_c[t];
      pr += acc[t][r] * ar_c[t];
    }
    pe += __shfl_xor(pe, 1); pr += __shfl_xor(pr, 1);
    pe += __shfl_xor(pe, 2); pr += __shfl_xor(pr, 2);
    pe += __shfl_xor(pe, 4); pr += __shfl_xor(pr, 4);
    pe += __shfl_xor(pe, 8); pr += __shfl_xor(pr, 8);
    if (col16 == 0 && row < M) {
      el[row] = pe;
      er[row] = pr;
    }
  }
}

// ============================ layer-0 aggregation (proven R12) ============================

__global__ __launch_bounds__(256) void agg0_kernel(
    const int* __restrict__ offs, const int* __restrict__ ssrc,
    const float* __restrict__ el, const float* __restrict__ er,
    const unsigned short* __restrict__ zb, const float* __restrict__ bias,
    unsigned short* __restrict__ outb, int n) {
  __shared__ float sW[4][16][4];
  __shared__ int   sS[4][16];
  int wid  = threadIdx.x >> 6;
  int lane = threadIdx.x & 63;
  int node = blockIdx.x * 4 + wid;
  if (node >= n) return;
  int c = lane & 3, eoff = lane >> 2;
  int half = lane >> 5, colg = lane & 31, h2 = colg >> 3;
  int s0 = offs[node], s1 = offs[node + 1];
  float er_c = er[node * 4 + c];

  float ssum = 0.f;
  float acc[8] = {0.f, 0.f, 0.f, 0.f, 0.f, 0.f, 0.f, 0.f};
  for (int base = s0; base < s1; base += 16) {
    int cnt = min(16, s1 - base);
    if (eoff < cnt) {
      int esrc = ssrc[base + eoff];
      float v = el[esrc * 4 + c] + er_c;
      v = v > 0.f ? v : 0.2f * v;              // leaky_relu(0.2)
      sW[wid][eoff][c] = expf(v);              // no max-shift (scores O(+-10))
      if (c == 0) sS[wid][eoff] = esrc;
    }
    for (int j = 0; j < cnt; j += 2) {
      int jj = j + half;
      float w = (jj < cnt) ? sW[wid][jj][h2] : 0.f;
      int sn = sS[wid][(jj < cnt) ? jj : (cnt - 1)];
      ssum += w;
      bf16x8 zu = *(const bf16x8*)(zb + (size_t)sn * 256 + (colg << 3));
      #pragma unroll
      for (int i = 0; i < 8; ++i)
        acc[i] += w * bf2f((unsigned short)zu[i]);
    }
  }

  ssum += __shfl_xor(ssum, 32);
  #pragma unroll
  for (int i = 0; i < 8; ++i) acc[i] += __shfl_xor(acc[i], 32);

  float inv = (s1 > s0) ? 1.f / ssum : 0.f;    // deg==0 -> out = bias
  if (half == 0) {
    const float4 b0v = *(const float4*)(bias + (colg << 3));
    const float4 b1v = *(const float4*)(bias + (colg << 3) + 4);
    float bb[8] = {b0v.x, b0v.y, b0v.z, b0v.w, b1v.x, b1v.y, b1v.z, b1v.w};
    bf16x8 u;
    #pragma unroll
    for (int i = 0; i < 8; ++i) {
      float o = acc[i] * inv + bb[i];
      o = o > 0.f ? o : expm1f(o);             // ELU
      u[i] = (short)f2bf(o);
    }
    *(bf16x8*)(outb + (size_t)node * 256 + (colg << 3)) = u;
  }
}

// ============================ layer-1 aggregation (proven R12) ============================

__global__ __launch_bounds__(256) void agg1_kernel(
    const int* __restrict__ offs, const int* __restrict__ ssrc,
    const float* __restrict__ el, const float* __restrict__ er,
    const unsigned short* __restrict__ zb, const float* __restrict__ bias,
    float* __restrict__ out, int n) {
  __shared__ float sW[4][64];
  __shared__ int   sS[4][64];
  int wid  = threadIdx.x >> 6;
  int lane = threadIdx.x & 63;
  int node = blockIdx.x * 4 + wid;
  if (node >= n) return;
  int half = lane >> 5, d = lane & 31;
  int s0 = offs[node], s1 = offs[node + 1];
  float ern = er[node];

  float ssum = 0.f;
  float2 acc = make_float2(0.f, 0.f);
  for (int base = s0; base < s1; base += 64) {
    int cnt = min(64, s1 - base);
    if (lane < cnt) {
      int esrc = ssrc[base + lane];
      float v = el[esrc] + ern;
      v = v > 0.f ? v : 0.2f * v;
      sW[wid][lane] = expf(v);                 // no max-shift
      sS[wid][lane] = esrc;
    }
    for (int j = 0; j < cnt; j += 2) {
      int jj = j + half;
      float w = (jj < cnt) ? sW[wid][jj] : 0.f;
      int sn = sS[wid][(jj < cnt) ? jj : (cnt - 1)];
      ssum += w;
      if (d < 20) {
        unsigned zp = *(const unsigned*)(zb + (size_t)sn * 40 + (d << 1));
        acc.x += w * bf2f((unsigned short)(zp & 0xffffu));
        acc.y += w * bf2f((unsigned short)(zp >> 16));
      }
    }
  }

  ssum  += __shfl_xor(ssum, 32);
  acc.x += __shfl_xor(acc.x, 32);
  acc.y += __shfl_xor(acc.y, 32);

  float inv = (s1 > s0) ? 1.f / ssum : 0.f;
  if (half == 0 && d < 20) {
    float2 o;
    o.x = acc.x * inv + bias[(d << 1) + 0];
    o.y = acc.y * inv + bias[(d << 1) + 1];
    *(float2*)(out + (size_t)node * 40 + (d << 1)) = o;
  }
}

// ============================ launch ============================

extern "C" void kernel_launch(void* const* d_in, const int* in_sizes, int n_in,
                              void* d_out, int out_size, void* d_ws, size_t ws_size,
                              hipStream_t stream) {
  const float* x   = (const float*)d_in[0];
  const int*   src = (const int*)d_in[1];
  const int*   dst = (const int*)d_in[2];
  const float* W0  = (const float*)d_in[3];
  const float* al0 = (const float*)d_in[4];
  const float* ar0 = (const float*)d_in[5];
  const float* b0  = (const float*)d_in[6];
  const float* W1  = (const float*)d_in[7];
  const float* al1 = (const float*)d_in[8];
  const float* ar1 = (const float*)d_in[9];
  const float* b1  = (const float*)d_in[10];
  float* out = (float*)d_out;

  const int N = in_sizes[0] / 256;   // 50000
  const int E = in_sizes[1];         // 800000
  const int NB = (N + 255) / 256;    // 196 scan blocks

  char* ws = (char*)d_ws;
  size_t off = 0;
  auto alloc = [&](size_t bytes) {
    void* p = ws + off;
    off = (off + bytes + 255) & ~(size_t)255;
    return p;
  };
  unsigned short* z0b = (unsigned short*)alloc((size_t)N * 256 * 2);
  unsigned short* h0b = (unsigned short*)alloc((size_t)N * 256 * 2);
  unsigned short* z1b = (unsigned short*)alloc((size_t)N * 40 * 2);
  unsigned short* w0p = (unsigned short*)alloc((size_t)16 * 8 * 64 * 8 * 2);
  unsigned short* w1p = (unsigned short*)alloc((size_t)3 * 8 * 64 * 8 * 2);
  float* el0  = (float*)alloc((size_t)N * 4 * 4);
  float* er0  = (float*)alloc((size_t)N * 4 * 4);
  float* el1  = (float*)alloc((size_t)N * 4);
  float* er1  = (float*)alloc((size_t)N * 4);
  int* deg    = (int*)alloc((size_t)N * 4);
  int* offs   = (int*)alloc((size_t)(N + 1) * 4);
  int* cursor = (int*)alloc((size_t)N * 4);
  int* bsum   = (int*)alloc((size_t)NB * 4);
  int* boffs  = (int*)alloc((size_t)NB * 4);
  int* ssrc   = (int*)alloc((size_t)E * 4);
  (void)off; (void)ws_size; (void)n_in; (void)out_size;

  const int nG = ((N + 127) / 128) * 2;          // 782 gemm0 blocks
  const int nH = (E + 255) / 256;                // 3125 hist blocks
  const int nC = 782;                            // csr blocks (grid-stride, ~4 edges/thread)

  // 1. deg = 0
  hipMemsetAsync(deg, 0, (size_t)N * 4, stream);
  // 2. pack || hist (no LDS -> full occupancy)
  mega0_kernel<<<38 + nH, 256, 0, stream>>>(W0, w0p, W1, w1p, dst, deg, E);
  // 3-5. exclusive scan, 3-phase (proven R5-R14)
  block_sum_kernel<<<NB, 256, 0, stream>>>(deg, bsum, N);
  scan_bsum_kernel<<<1, 1024, 0, stream>>>(bsum, boffs, offs, NB, N);
  write_offsets_kernel<<<NB, 256, 0, stream>>>(deg, boffs, offs, cursor, N);
  // 6. gemm0 || build_csr (independent work overlapped)
  mega2_kernel<<<nG + nC, 256, 0, stream>>>(x, w0p, z0b, al0, ar0, el0, er0, N,
                                            src, dst, cursor, ssrc, E, nG, nC);
  // 7. layer-0 aggregation + ELU -> h0b
  agg0_kernel<<<(N + 3) / 4, 256, 0, stream>>>(offs, ssrc, el0, er0, z0b, b0, h0b, N);
  // 8. layer-1 GEMM + fused el/er
  gemm1_mfma_kernel<<<(N + 63) / 64, 256, 0, stream>>>(h0b, w1p, z1b, al1, ar1, el1, er1, N);
  // 9. layer-1 aggregation -> out
  agg1_kernel<<<(N + 3) / 4, 256, 0, stream>>>(offs, ssrc, el1, er1, z1b, b1, out, N);
}

// Round 17
// 319.787 us; speedup vs baseline: 1.0716x; 1.0081x over previous
//
#include <hip/hip_runtime.h>
#include <math.h>

using bf16x8 = __attribute__((ext_vector_type(8))) short;
using f32x4  = __attribute__((ext_vector_type(4))) float;

// ---- bf16 helpers ----
__device__ __forceinline__ unsigned short f2bf(float v) {          // RNE pack
  unsigned int b = __float_as_uint(v);
  unsigned int r = (b + 0x7fffu + ((b >> 16) & 1u)) >> 16;
  return (unsigned short)r;
}
__device__ __forceinline__ float bf2f(unsigned short u) {
  return __uint_as_float(((unsigned int)u) << 16);
}

// ============================ mega0: pack (blocks 0..37) || hist (blocks 38..) (proven R16) ============================

__global__ void mega0_kernel(const float* __restrict__ W0f, unsigned short* __restrict__ Bp0,
                             const float* __restrict__ W1f, unsigned short* __restrict__ Bp1,
                             const int* __restrict__ dst, int* __restrict__ deg, int E) {
  int bx = blockIdx.x;
  if (bx >= 38) {                                // ---- hist ----
    int t = (bx - 38) * 256 + threadIdx.x;
    if (t < E) atomicAdd(&deg[dst[t]], 1);
    return;
  }
  int idx = bx * 256 + threadIdx.x;
  if (idx < 8192) {
    int lane = idx & 63, s = (idx >> 6) & 7, t = idx >> 9;
    int n = t * 16 + (lane & 15), quad = lane >> 4;
    unsigned short* o = Bp0 + (size_t)idx * 8;
    #pragma unroll
    for (int j = 0; j < 8; ++j) {
      int k = s * 32 + quad * 8 + j;
      o[j] = f2bf(W0f[(size_t)k * 256 + n]);
    }
  } else if (idx < 8192 + 1536) {
    int i1 = idx - 8192;
    int lane = i1 & 63, s = (i1 >> 6) & 7, t = i1 >> 9;
    int n = t * 16 + (lane & 15), quad = lane >> 4;
    unsigned short* o = Bp1 + (size_t)i1 * 8;
    #pragma unroll
    for (int j = 0; j < 8; ++j) {
      int k = s * 32 + quad * 8 + j;
      o[j] = (n < 40) ? f2bf(W1f[(size_t)k * 40 + n]) : 0;
    }
  }
}

// ============================ 3-phase parallel scan (proven R5-R16) ============================

__global__ void block_sum_kernel(const int* __restrict__ deg, int* __restrict__ bsum, int n) {
  __shared__ int red[4];
  int t = threadIdx.x, i = blockIdx.x * 256 + t;
  int v = (i < n) ? deg[i] : 0;
  #pragma unroll
  for (int off = 32; off; off >>= 1) v += __shfl_xor(v, off);
  if ((t & 63) == 0) red[t >> 6] = v;
  __syncthreads();
  if (t == 0) bsum[blockIdx.x] = red[0] + red[1] + red[2] + red[3];
}

__global__ void scan_bsum_kernel(const int* __restrict__ bsum, int* __restrict__ boffs,
                                 int* __restrict__ offsets, int nb, int n) {
  __shared__ int tmp[1024];
  int t = threadIdx.x;
  int v = (t < nb) ? bsum[t] : 0;
  tmp[t] = v;
  __syncthreads();
  #pragma unroll
  for (int off = 1; off < 1024; off <<= 1) {
    int add = (t >= off) ? tmp[t - off] : 0;
    __syncthreads();
    tmp[t] += add;
    __syncthreads();
  }
  if (t < nb) boffs[t] = tmp[t] - v;
  if (t == 1023) offsets[n] = tmp[1023];
}

__global__ void write_offsets_kernel(const int* __restrict__ deg, const int* __restrict__ boffs,
                                     int* __restrict__ offsets, int* __restrict__ cursor, int n) {
  __shared__ int tmp[256];
  int t = threadIdx.x, i = blockIdx.x * 256 + t;
  int v = (i < n) ? deg[i] : 0;
  tmp[t] = v;
  __syncthreads();
  #pragma unroll
  for (int off = 1; off < 256; off <<= 1) {
    int add = (t >= off) ? tmp[t - off] : 0;
    __syncthreads();
    tmp[t] += add;
    __syncthreads();
  }
  if (i < n) {
    int o = boffs[blockIdx.x] + tmp[t] - v;
    offsets[i] = o;
    cursor[i] = o;
  }
}

// ============================ mega2 v2: 512-thread blocks ============================
// gemm part (bx < nG): 256 rows x 128-col half per block, 8 waves (4 row x 2 col);
// 64 KB LDS amortized over 8 waves -> 2 blocks/CU = 16 waves/CU (2x R16).
// csr part (bx >= nG): grid-stride scatter at 512 threads/block.

__global__ __launch_bounds__(512) void mega2_kernel(
    const float* __restrict__ A, const unsigned short* __restrict__ Bp,
    unsigned short* __restrict__ Zb,
    const float* __restrict__ al, const float* __restrict__ arr,
    float* __restrict__ el, float* __restrict__ er, int M,
    const int* __restrict__ src, const int* __restrict__ dst,
    int* __restrict__ cursor, int* __restrict__ ssrc, int E, int nG, int nC) {
  __shared__ unsigned short Bs[32768];           // 64 KB: this col-half of packed W0
  int bx = blockIdx.x;
  int tid = threadIdx.x;

  if (bx >= nG) {                                // ---- build_csr part ----
    int stride = nC * 512;
    for (int e = (bx - nG) * 512 + tid; e < E; e += stride) {
      int p = atomicAdd(&cursor[dst[e]], 1);
      ssrc[p] = src[e];
    }
    return;
  }

  // ---- gemm0 part ----
  int gx = bx >> 1, y = bx & 1;
  {                                              // stage 64 KB = 4096 int4, 512 thr x 8
    const int4* s4 = (const int4*)(Bp + (size_t)y * 32768);
    int4* d4 = (int4*)Bs;
    #pragma unroll
    for (int i = 0; i < 8; ++i) d4[tid + i * 512] = s4[tid + i * 512];
  }
  __syncthreads();

  int wid = tid >> 6, lane = tid & 63;
  int quad = lane >> 4, col16 = lane & 15;
  int wr = wid >> 1, wc = wid & 1;               // 4 row-waves x 2 col-waves
  int rowbase = gx * 256 + wr * 64;

  // clamped row pointers (branch-free A loads; clamped rows only affect unwritten C-rows)
  const float* aptr[4];
  #pragma unroll
  for (int rt = 0; rt < 4; ++rt) {
    int m = rowbase + rt * 16 + col16;
    if (m > M - 1) m = M - 1;
    aptr[rt] = A + (size_t)m * 256 + quad * 8;
  }

  f32x4 acc[4][4];
  #pragma unroll
  for (int rt = 0; rt < 4; ++rt)
    #pragma unroll
    for (int ct = 0; ct < 4; ++ct) acc[rt][ct] = {0.f, 0.f, 0.f, 0.f};

  const bf16x8* BsV = (const bf16x8*)Bs;

  auto loadA = [&](bf16x8* fr, int s) {
    #pragma unroll
    for (int rt = 0; rt < 4; ++rt) {
      const float* ap = aptr[rt] + s * 32;
      float4 a0 = *(const float4*)ap;
      float4 a1 = *(const float4*)(ap + 4);
      fr[rt][0] = (short)f2bf(a0.x); fr[rt][1] = (short)f2bf(a0.y);
      fr[rt][2] = (short)f2bf(a0.z); fr[rt][3] = (short)f2bf(a0.w);
      fr[rt][4] = (short)f2bf(a1.x); fr[rt][5] = (short)f2bf(a1.y);
      fr[rt][6] = (short)f2bf(a1.z); fr[rt][7] = (short)f2bf(a1.w);
    }
  };

  bf16x8 afc[4];
  loadA(afc, 0);
  for (int s = 0; s < 8; ++s) {
    bf16x8 afn[4];
    if (s < 7) loadA(afn, s + 1);                // prefetch next k-step
    #pragma unroll
    for (int ct = 0; ct < 4; ++ct) {
      bf16x8 bf = BsV[((wc * 4 + ct) * 8 + s) * 64 + lane];
      #pragma unroll
      for (int rt = 0; rt < 4; ++rt)
        acc[rt][ct] = __builtin_amdgcn_mfma_f32_16x16x32_bf16(afc[rt], bf, acc[rt][ct], 0, 0, 0);
    }
    if (s < 7) {
      #pragma unroll
      for (int rt = 0; rt < 4; ++rt) afc[rt] = afn[rt];
    }
  }

  int hw = y * 2 + wc;
  float al_c[4], ar_c[4];
  #pragma unroll
  for (int ct = 0; ct < 4; ++ct) {
    int col = y * 128 + (wc * 4 + ct) * 16 + col16;
    al_c[ct] = al[col];
    ar_c[ct] = arr[col];
  }

  #pragma unroll
  for (int rt = 0; rt < 4; ++rt) {
    int row0 = rowbase + rt * 16 + quad * 4;
    #pragma unroll
    for (int r = 0; r < 4; ++r) {
      int row = row0 + r;
      if (row < M) {
        #pragma unroll
        for (int ct = 0; ct < 4; ++ct) {
          int col = y * 128 + (wc * 4 + ct) * 16 + col16;
          Zb[(size_t)row * 256 + col] = f2bf(acc[rt][ct][r]);
        }
      }
      float pe = 0.f, pr = 0.f;
      #pragma unroll
      for (int ct = 0; ct < 4; ++ct) {
        float zv = acc[rt][ct][r];
        pe += zv * al_c[ct];
        pr += zv * ar_c[ct];
      }
      pe += __shfl_xor(pe, 1); pr += __shfl_xor(pr, 1);
      pe += __shfl_xor(pe, 2); pr += __shfl_xor(pr, 2);
      pe += __shfl_xor(pe, 4); pr += __shfl_xor(pr, 4);
      pe += __shfl_xor(pe, 8); pr += __shfl_xor(pr, 8);
      if (col16 == 0 && row < M) {
        el[(size_t)row * 4 + hw] = pe;
        er[(size_t)row * 4 + hw] = pr;
      }
    }
  }
}

// ============================ layer-1 GEMM (proven R9) ============================

__global__ __launch_bounds__(256) void gemm1_mfma_kernel(
    const unsigned short* __restrict__ Ab, const unsigned short* __restrict__ Bp,
    unsigned short* __restrict__ Zb,
    const float* __restrict__ al, const float* __restrict__ arr,
    float* __restrict__ el, float* __restrict__ er, int M) {
  int wid = threadIdx.x >> 6, lane = threadIdx.x & 63;
  int quad = lane >> 4, col16 = lane & 15;
  int m = blockIdx.x * 64 + wid * 16 + col16;

  f32x4 acc[3];
  #pragma unroll
  for (int t = 0; t < 3; ++t) acc[t] = {0.f, 0.f, 0.f, 0.f};

  const bf16x8* BpV = (const bf16x8*)Bp;

  for (int s = 0; s < 8; ++s) {
    bf16x8 af;
    if (m < M) {
      af = *(const bf16x8*)(Ab + (size_t)m * 256 + s * 32 + quad * 8);
    } else {
      #pragma unroll
      for (int j = 0; j < 8; ++j) af[j] = 0;
    }
    #pragma unroll
    for (int t = 0; t < 3; ++t) {
      bf16x8 bf = BpV[(t * 8 + s) * 64 + lane];
      acc[t] = __builtin_amdgcn_mfma_f32_16x16x32_bf16(af, bf, acc[t], 0, 0, 0);
    }
  }

  float al_c[3], ar_c[3];
  #pragma unroll
  for (int t = 0; t < 3; ++t) {
    int col = t * 16 + col16;
    al_c[t] = (col < 40) ? al[col] : 0.f;
    ar_c[t] = (col < 40) ? arr[col] : 0.f;
  }

  int row0 = blockIdx.x * 64 + wid * 16 + quad * 4;
  #pragma unroll
  for (int r = 0; r < 4; ++r) {
    int row = row0 + r;
    if (row < M) {
      #pragma unroll
      for (int t = 0; t < 3; ++t) {
        int col = t * 16 + col16;
        if (col < 40) Zb[(size_t)row * 40 + col] = f2bf(acc[t][r]);
      }
    }
    float pe = 0.f, pr = 0.f;
    #pragma unroll
    for (int t = 0; t < 3; ++t) {
      pe += acc[t][r] * al_c[t];
      pr += acc[t][r] * ar_c[t];
    }
    pe += __shfl_xor(pe, 1); pr += __shfl_xor(pr, 1);
    pe += __shfl_xor(pe, 2); pr += __shfl_xor(pr, 2);
    pe += __shfl_xor(pe, 4); pr += __shfl_xor(pr, 4);
    pe += __shfl_xor(pe, 8); pr += __shfl_xor(pr, 8);
    if (col16 == 0 && row < M) {
      el[row] = pe;
      er[row] = pr;
    }
  }
}

// ============================ layer-0 aggregation (proven R12) ============================

__global__ __launch_bounds__(256) void agg0_kernel(
    const int* __restrict__ offs, const int* __restrict__ ssrc,
    const float* __restrict__ el, const float* __restrict__ er,
    const unsigned short* __restrict__ zb, const float* __restrict__ bias,
    unsigned short* __restrict__ outb, int n) {
  __shared__ float sW[4][16][4];
  __shared__ int   sS[4][16];
  int wid  = threadIdx.x >> 6;
  int lane = threadIdx.x & 63;
  int node = blockIdx.x * 4 + wid;
  if (node >= n) return;
  int c = lane & 3, eoff = lane >> 2;
  int half = lane >> 5, colg = lane & 31, h2 = colg >> 3;
  int s0 = offs[node], s1 = offs[node + 1];
  float er_c = er[node * 4 + c];

  float ssum = 0.f;
  float acc[8] = {0.f, 0.f, 0.f, 0.f, 0.f, 0.f, 0.f, 0.f};
  for (int base = s0; base < s1; base += 16) {
    int cnt = min(16, s1 - base);
    if (eoff < cnt) {
      int esrc = ssrc[base + eoff];
      float v = el[esrc * 4 + c] + er_c;
      v = v > 0.f ? v : 0.2f * v;              // leaky_relu(0.2)
      sW[wid][eoff][c] = expf(v);              // no max-shift (scores O(+-10))
      if (c == 0) sS[wid][eoff] = esrc;
    }
    for (int j = 0; j < cnt; j += 2) {
      int jj = j + half;
      float w = (jj < cnt) ? sW[wid][jj][h2] : 0.f;
      int sn = sS[wid][(jj < cnt) ? jj : (cnt - 1)];
      ssum += w;
      bf16x8 zu = *(const bf16x8*)(zb + (size_t)sn * 256 + (colg << 3));
      #pragma unroll
      for (int i = 0; i < 8; ++i)
        acc[i] += w * bf2f((unsigned short)zu[i]);
    }
  }

  ssum += __shfl_xor(ssum, 32);
  #pragma unroll
  for (int i = 0; i < 8; ++i) acc[i] += __shfl_xor(acc[i], 32);

  float inv = (s1 > s0) ? 1.f / ssum : 0.f;    // deg==0 -> out = bias
  if (half == 0) {
    const float4 b0v = *(const float4*)(bias + (colg << 3));
    const float4 b1v = *(const float4*)(bias + (colg << 3) + 4);
    float bb[8] = {b0v.x, b0v.y, b0v.z, b0v.w, b1v.x, b1v.y, b1v.z, b1v.w};
    bf16x8 u;
    #pragma unroll
    for (int i = 0; i < 8; ++i) {
      float o = acc[i] * inv + bb[i];
      o = o > 0.f ? o : expm1f(o);             // ELU
      u[i] = (short)f2bf(o);
    }
    *(bf16x8*)(outb + (size_t)node * 256 + (colg << 3)) = u;
  }
}

// ============================ layer-1 aggregation (proven R12) ============================

__global__ __launch_bounds__(256) void agg1_kernel(
    const int* __restrict__ offs, const int* __restrict__ ssrc,
    const float* __restrict__ el, const float* __restrict__ er,
    const unsigned short* __restrict__ zb, const float* __restrict__ bias,
    float* __restrict__ out, int n) {
  __shared__ float sW[4][64];
  __shared__ int   sS[4][64];
  int wid  = threadIdx.x >> 6;
  int lane = threadIdx.x & 63;
  int node = blockIdx.x * 4 + wid;
  if (node >= n) return;
  int half = lane >> 5, d = lane & 31;
  int s0 = offs[node], s1 = offs[node + 1];
  float ern = er[node];

  float ssum = 0.f;
  float2 acc = make_float2(0.f, 0.f);
  for (int base = s0; base < s1; base += 64) {
    int cnt = min(64, s1 - base);
    if (lane < cnt) {
      int esrc = ssrc[base + lane];
      float v = el[esrc] + ern;
      v = v > 0.f ? v : 0.2f * v;
      sW[wid][lane] = expf(v);                 // no max-shift
      sS[wid][lane] = esrc;
    }
    for (int j = 0; j < cnt; j += 2) {
      int jj = j + half;
      float w = (jj < cnt) ? sW[wid][jj] : 0.f;
      int sn = sS[wid][(jj < cnt) ? jj : (cnt - 1)];
      ssum += w;
      if (d < 20) {
        unsigned zp = *(const unsigned*)(zb + (size_t)sn * 40 + (d << 1));
        acc.x += w * bf2f((unsigned short)(zp & 0xffffu));
        acc.y += w * bf2f((unsigned short)(zp >> 16));
      }
    }
  }

  ssum  += __shfl_xor(ssum, 32);
  acc.x += __shfl_xor(acc.x, 32);
  acc.y += __shfl_xor(acc.y, 32);

  float inv = (s1 > s0) ? 1.f / ssum : 0.f;
  if (half == 0 && d < 20) {
    float2 o;
    o.x = acc.x * inv + bias[(d << 1) + 0];
    o.y = acc.y * inv + bias[(d << 1) + 1];
    *(float2*)(out + (size_t)node * 40 + (d << 1)) = o;
  }
}

// ============================ launch ============================

extern "C" void kernel_launch(void* const* d_in, const int* in_sizes, int n_in,
                              void* d_out, int out_size, void* d_ws, size_t ws_size,
                              hipStream_t stream) {
  const float* x   = (const float*)d_in[0];
  const int*   src = (const int*)d_in[1];
  const int*   dst = (const int*)d_in[2];
  const float* W0  = (const float*)d_in[3];
  const float* al0 = (const float*)d_in[4];
  const float* ar0 = (const float*)d_in[5];
  const float* b0  = (const float*)d_in[6];
  const float* W1  = (const float*)d_in[7];
  const float* al1 = (const float*)d_in[8];
  const float* ar1 = (const float*)d_in[9];
  const float* b1  = (const float*)d_in[10];
  float* out = (float*)d_out;

  const int N = in_sizes[0] / 256;   // 50000
  const int E = in_sizes[1];         // 800000
  const int NB = (N + 255) / 256;    // 196 scan blocks

  char* ws = (char*)d_ws;
  size_t off = 0;
  auto alloc = [&](size_t bytes) {
    void* p = ws + off;
    off = (off + bytes + 255) & ~(size_t)255;
    return p;
  };
  unsigned short* z0b = (unsigned short*)alloc((size_t)N * 256 * 2);
  unsigned short* h0b = (unsigned short*)alloc((size_t)N * 256 * 2);
  unsigned short* z1b = (unsigned short*)alloc((size_t)N * 40 * 2);
  unsigned short* w0p = (unsigned short*)alloc((size_t)16 * 8 * 64 * 8 * 2);
  unsigned short* w1p = (unsigned short*)alloc((size_t)3 * 8 * 64 * 8 * 2);
  float* el0  = (float*)alloc((size_t)N * 4 * 4);
  float* er0  = (float*)alloc((size_t)N * 4 * 4);
  float* el1  = (float*)alloc((size_t)N * 4);
  float* er1  = (float*)alloc((size_t)N * 4);
  int* deg    = (int*)alloc((size_t)N * 4);
  int* offs   = (int*)alloc((size_t)(N + 1) * 4);
  int* cursor = (int*)alloc((size_t)N * 4);
  int* bsum   = (int*)alloc((size_t)NB * 4);
  int* boffs  = (int*)alloc((size_t)NB * 4);
  int* ssrc   = (int*)alloc((size_t)E * 4);
  (void)off; (void)ws_size; (void)n_in; (void)out_size;

  const int nG = ((N + 255) / 256) * 2;          // 392 gemm0 blocks (256 rows x col-half)
  const int nH = (E + 255) / 256;                // 3125 hist blocks
  const int nC = 391;                            // csr blocks (512 thr, ~4 edges/thread)

  // 1. deg = 0
  hipMemsetAsync(deg, 0, (size_t)N * 4, stream);
  // 2. pack || hist (no LDS -> full occupancy)
  mega0_kernel<<<38 + nH, 256, 0, stream>>>(W0, w0p, W1, w1p, dst, deg, E);
  // 3-5. exclusive scan, 3-phase
  block_sum_kernel<<<NB, 256, 0, stream>>>(deg, bsum, N);
  scan_bsum_kernel<<<1, 1024, 0, stream>>>(bsum, boffs, offs, NB, N);
  write_offsets_kernel<<<NB, 256, 0, stream>>>(deg, boffs, offs, cursor, N);
  // 6. gemm0 || build_csr, 512-thread blocks (16 waves/CU for the gemm part)
  mega2_kernel<<<nG + nC, 512, 0, stream>>>(x, w0p, z0b, al0, ar0, el0, er0, N,
                                            src, dst, cursor, ssrc, E, nG, nC);
  // 7. layer-0 aggregation + ELU -> h0b
  agg0_kernel<<<(N + 3) / 4, 256, 0, stream>>>(offs, ssrc, el0, er0, z0b, b0, h0b, N);
  // 8. layer-1 GEMM + fused el/er
  gemm1_mfma_kernel<<<(N + 63) / 64, 256, 0, stream>>>(h0b, w1p, z1b, al1, ar1, el1, er1, N);
  // 9. layer-1 aggregation -> out
  agg1_kernel<<<(N + 3) / 4, 256, 0, stream>>>(offs, ssrc, el1, er1, z1b, b1, out, N);
}